// Round 23
// baseline (1479.213 us; speedup 1.0000x reference)
//
#include <hip/hip_runtime.h>
#include <hip/hip_bf16.h>

#define B_ 32
#define T_ 6
#define C_ 128
#define H_ 32
#define W_ 32
#define HW_ (H_ * W_)
#define CHW_ (C_ * H_ * W_)
#define NIMG_ (B_ * T_)       // 192
#define WELEM_ (C_ * C_ * 9)  // 147456
#define KTOT_ (C_ * 9)        // 1152
// Reference semantics (VERIFIED round 21): im2col + OpenBLAS SKYLAKEX sgemm,
// k = (kh*3+kw)*128 + ci (taps row-major, ci fastest), FMA chains,
// Q=192 panels (6 equal), C += panel joins, bias after, clamp after.

typedef __attribute__((ext_vector_type(8))) short bf16x8;
typedef __attribute__((ext_vector_type(4))) float f32x4;

// Uncontractable fp32 add (separate IEEE rounding: panel joins, bias, scan).
__device__ __forceinline__ float add_rn_hw(float a, float b) {
    float d;
    asm volatile("v_add_f32 %0, %1, %2" : "=v"(d) : "v"(a), "v"(b));
    return d;
}

__device__ __forceinline__ unsigned short f2bf(float x) {
    __hip_bfloat16 h = __float2bfloat16(x);
    return *reinterpret_cast<unsigned short*>(&h);
}

// ---------------------------------------------------------------------------
// Pre-conv weights: [O, I, 3, 3] -> [k][O] with k = (kh*3 + kw)*C + ci
__global__ void transpose_w_kio_kernel(const float* __restrict__ w,
                                       float* __restrict__ wt) {
    int idx = blockIdx.x * blockDim.x + threadIdx.x;
    if (idx >= WELEM_) return;
    int o  = idx / (C_ * 9);
    int ci = (idx % (C_ * 9)) / 9;
    int kt = idx % 9;
    wt[(size_t)(kt * C_ + ci) * C_ + o] = w[idx];
}

// ---------------------------------------------------------------------------
// Post-conv weights -> MFMA fragment order, split w = hi + lo (bf16 pair).
__global__ void pack_w_post_kernel(const float* __restrict__ w,
                                   unsigned short* __restrict__ hi,
                                   unsigned short* __restrict__ lo) {
    int idx = blockIdx.x * blockDim.x + threadIdx.x;
    if (idx >= WELEM_) return;
    int j     = idx & 7;
    int lane  = (idx >> 3) & 63;
    int ct    = (idx >> 9) & 7;
    int chunk = idx >> 12;            // 0..35
    int kt = chunk >> 2;
    int cb = chunk & 3;
    int co = ct * 16 + (lane & 15);
    int ci = cb * 32 + ((lane >> 4) << 3) + j;
    float v = w[(size_t)(co * C_ + ci) * 9 + kt];
    unsigned short h = f2bf(v);
    __hip_bfloat16 hb = *reinterpret_cast<__hip_bfloat16*>(&h);
    float rest = v - __bfloat162float(hb);
    hi[idx] = h;
    lo[idx] = f2bf(rest);
}

// ---------------------------------------------------------------------------
// Pre-conv: bit-exact R21 arithmetic, restructured with STATIC segments and
// 1-deep weight prefetch so the compiler can pipeline the L2 loads.
// Segment = (tap row TR, tap col TC, tap index KT, ci0, cnt); panel joins at
// the same k = 192*p boundaries; per-output fmaf chain order is IDENTICAL.

#define SEG(TR, TC, KT, CI0, CNT)                                             \
    do {                                                                      \
        const float* xp = &xs[((CI0) * 3 + (TR)) * 34 + wb + (TC)];           \
        const float* wp = wt + (size_t)((KT) * C_ + (CI0)) * C_ + co;         \
        float4 wv = *reinterpret_cast<const float4*>(wp);                     \
        _Pragma("unroll 4")                                                   \
        for (int c = 0; c < (CNT); ++c) {                                     \
            float4 wn = wv;                                                   \
            if (c + 1 < (CNT)) {                                              \
                wn = *reinterpret_cast<const float4*>(wp + C_);               \
            }                                                                 \
            float x0 = xp[0], x1 = xp[1], x2 = xp[2], x3 = xp[3];             \
            sub[0][0] = fmaf(x0, wv.x, sub[0][0]);                            \
            sub[0][1] = fmaf(x1, wv.x, sub[0][1]);                            \
            sub[0][2] = fmaf(x2, wv.x, sub[0][2]);                            \
            sub[0][3] = fmaf(x3, wv.x, sub[0][3]);                            \
            sub[1][0] = fmaf(x0, wv.y, sub[1][0]);                            \
            sub[1][1] = fmaf(x1, wv.y, sub[1][1]);                            \
            sub[1][2] = fmaf(x2, wv.y, sub[1][2]);                            \
            sub[1][3] = fmaf(x3, wv.y, sub[1][3]);                            \
            sub[2][0] = fmaf(x0, wv.z, sub[2][0]);                            \
            sub[2][1] = fmaf(x1, wv.z, sub[2][1]);                            \
            sub[2][2] = fmaf(x2, wv.z, sub[2][2]);                            \
            sub[2][3] = fmaf(x3, wv.z, sub[2][3]);                            \
            sub[3][0] = fmaf(x0, wv.w, sub[3][0]);                            \
            sub[3][1] = fmaf(x1, wv.w, sub[3][1]);                            \
            sub[3][2] = fmaf(x2, wv.w, sub[3][2]);                            \
            sub[3][3] = fmaf(x3, wv.w, sub[3][3]);                            \
            wv = wn; wp += C_; xp += 102;                                     \
        }                                                                     \
    } while (0)

#define JOIN()                                                                \
    do {                                                                      \
        _Pragma("unroll")                                                     \
        for (int j = 0; j < 4; ++j)                                           \
            _Pragma("unroll")                                                 \
            for (int q = 0; q < 4; ++q) {                                     \
                tot[j][q] = add_rn_hw(tot[j][q], sub[j][q]);                  \
                sub[j][q] = 0.f;                                              \
            }                                                                 \
    } while (0)

__global__ __launch_bounds__(256)
void conv_pre_blas_kernel(const float* __restrict__ in,   // [N, C, H, W]
                          const float* __restrict__ wt,   // [k][O]
                          const float* __restrict__ bias, // [O]
                          const float* __restrict__ alpha_p,
                          float* __restrict__ out) {      // [N, C, H, W]
    __shared__ float xs[C_ * 3 * 34];

    const int blk = blockIdx.x;      // n * H + h
    const int n = blk / H_;
    const int h = blk % H_;
    const int tid = threadIdx.x;

    const float* inbase = in + (size_t)n * CHW_;
    for (int i = tid; i < C_ * 3 * 8; i += 256) {
        int c  = i / 24;
        int rr = (i % 24) / 8;
        int w4 = i % 8;
        int hh = h + rr - 1;
        float4 v = make_float4(0.f, 0.f, 0.f, 0.f);
        if (hh >= 0 && hh < H_) {
            v = *reinterpret_cast<const float4*>(inbase + c * HW_ + hh * W_ + w4 * 4);
        }
        float* dst = &xs[(c * 3 + rr) * 34 + 1 + w4 * 4];
        dst[0] = v.x; dst[1] = v.y; dst[2] = v.z; dst[3] = v.w;
    }
    for (int i = tid; i < C_ * 3 * 2; i += 256) {
        int cr = i >> 1;
        int side = i & 1;
        xs[cr * 34 + side * 33] = 0.f;
    }
    __syncthreads();

    const int co = (tid >> 3) * 4;   // c_out base
    const int wb = (tid & 7) * 4;    // w base

    float tot[4][4], sub[4][4];
#pragma unroll
    for (int j = 0; j < 4; ++j)
#pragma unroll
        for (int q = 0; q < 4; ++q) { tot[j][q] = 0.f; sub[j][q] = 0.f; }

    // Panel 0: k [0,192)   = kt0 ci[0,128) + kt1 ci[0,64)
    SEG(0, 0, 0, 0, 128);  SEG(0, 1, 1, 0, 64);    JOIN();
    // Panel 1: k [192,384) = kt1 ci[64,128) + kt2 ci[0,128)
    SEG(0, 1, 1, 64, 64);  SEG(0, 2, 2, 0, 128);   JOIN();
    // Panel 2: k [384,576) = kt3 ci[0,128) + kt4 ci[0,64)
    SEG(1, 0, 3, 0, 128);  SEG(1, 1, 4, 0, 64);    JOIN();
    // Panel 3: k [576,768) = kt4 ci[64,128) + kt5 ci[0,128)
    SEG(1, 1, 4, 64, 64);  SEG(1, 2, 5, 0, 128);   JOIN();
    // Panel 4: k [768,960) = kt6 ci[0,128) + kt7 ci[0,64)
    SEG(2, 0, 6, 0, 128);  SEG(2, 1, 7, 0, 64);    JOIN();
    // Panel 5: k [960,1152)= kt7 ci[64,128) + kt8 ci[0,128)
    SEG(2, 1, 7, 64, 64);  SEG(2, 2, 8, 0, 128);   JOIN();

    const float alpha = *alpha_p;
    float* outbase = out + (size_t)n * CHW_ + (size_t)h * W_ + wb;
#pragma unroll
    for (int j = 0; j < 4; ++j) {
        float bj = bias[co + j];
        float4 v;
#pragma unroll
        for (int q = 0; q < 4; ++q) {
            float y = add_rn_hw(tot[j][q], bj);
            y = fminf(fmaxf(y, 0.f), alpha);
            (&v.x)[q] = y;
        }
        *reinterpret_cast<float4*>(outbase + (size_t)(co + j) * HW_) = v;
    }
}

// ---------------------------------------------------------------------------
// Spiking scan over T, fp32 (bit-exact — VERIFIED round 21, unchanged).
__global__ __launch_bounds__(256)
void spike_scan_kernel(float* __restrict__ ybuf,
                       const float* __restrict__ alpha_p) {
    int idx = blockIdx.x * blockDim.x + threadIdx.x;
    if (idx >= B_ * CHW_) return;
    int b = idx / CHW_;
    int r = idx % CHW_;
    const float thr = *alpha_p;

    float mem = 0.5f * thr;
    float ss = 0.f;
    size_t base = (size_t)b * T_ * CHW_ + r;
#pragma unroll
    for (int t = 0; t < T_; ++t) {
        float xt = ybuf[base + (size_t)t * CHW_];
        mem = add_rn_hw(mem, xt);
        float sp = (mem >= thr) ? 1.f : 0.f;
        mem = mem - thr * sp;
        ss = ss + sp;
        float inh = ((mem <= -0.001f) && (ss > 0.f)) ? 1.f : 0.f;
        mem = mem + thr * inh;
        ss = ss - inh;
        ybuf[base + (size_t)t * CHW_] = (sp - inh) * thr;
    }
}

// ---------------------------------------------------------------------------
// Post-conv via bf16 MFMA, hi+lo weight split (VERIFIED round 22, unchanged).
__global__ __launch_bounds__(256)
void conv_post_mfma_kernel(const float* __restrict__ ybuf,
                           const unsigned short* __restrict__ pk_hi,
                           const unsigned short* __restrict__ pk_lo,
                           const float* __restrict__ bias,
                           float* __restrict__ out) {
    __shared__ unsigned short sp[4 * 34 * 136];

    const int n  = blockIdx.x >> 4;
    const int h2 = blockIdx.x & 15;
    const int h0 = h2 * 2;
    const int tid = threadIdx.x;

    for (int p = tid; p < 512; p += 256) {
        int row = p >> 7, ci = p & 127;
        int gh = h0 - 1 + row;
        unsigned short* dst = &sp[(row * 34) * 136 + ci];
        if (gh >= 0 && gh < H_) {
            const float* src = ybuf + (((size_t)n * C_ + ci) * H_ + gh) * W_;
            dst[0] = 0;
#pragma unroll
            for (int w4 = 0; w4 < 8; ++w4) {
                float4 v = *reinterpret_cast<const float4*>(src + w4 * 4);
                dst[(1 + w4 * 4 + 0) * 136] = f2bf(v.x);
                dst[(1 + w4 * 4 + 1) * 136] = f2bf(v.y);
                dst[(1 + w4 * 4 + 2) * 136] = f2bf(v.z);
                dst[(1 + w4 * 4 + 3) * 136] = f2bf(v.w);
            }
            dst[33 * 136] = 0;
        } else {
#pragma unroll
            for (int w = 0; w < 34; ++w) dst[w * 136] = 0;
        }
    }
    __syncthreads();

    const int wave = tid >> 6, lane = tid & 63;
    const int l15 = lane & 15, l4 = lane >> 4;

    f32x4 acc[2][4];
#pragma unroll
    for (int ct = 0; ct < 2; ++ct)
#pragma unroll
        for (int t = 0; t < 4; ++t) acc[ct][t] = (f32x4){0.f, 0.f, 0.f, 0.f};

    for (int kt = 0; kt < 9; ++kt) {
        const int tr = kt / 3, tc = kt % 3;
#pragma unroll
        for (int cb = 0; cb < 4; ++cb) {
            const int chunk = kt * 4 + cb;
            bf16x8 bf[4];
#pragma unroll
            for (int t = 0; t < 4; ++t) {
                int rsp = (t >> 1) + tr;
                int wsp = (t & 1) * 16 + l15 + tc;
                bf[t] = *reinterpret_cast<const bf16x8*>(
                    &sp[(rsp * 34 + wsp) * 136 + cb * 32 + l4 * 8]);
            }
            const unsigned short* pa = pk_hi + ((size_t)(chunk * 8 + wave * 2) * 64 + lane) * 8;
            const unsigned short* pl = pk_lo + ((size_t)(chunk * 8 + wave * 2) * 64 + lane) * 8;
            bf16x8 ah0 = *reinterpret_cast<const bf16x8*>(pa);
            bf16x8 ah1 = *reinterpret_cast<const bf16x8*>(pa + 512);
            bf16x8 al0 = *reinterpret_cast<const bf16x8*>(pl);
            bf16x8 al1 = *reinterpret_cast<const bf16x8*>(pl + 512);
#pragma unroll
            for (int t = 0; t < 4; ++t) {
                acc[0][t] = __builtin_amdgcn_mfma_f32_16x16x32_bf16(ah0, bf[t], acc[0][t], 0, 0, 0);
                acc[1][t] = __builtin_amdgcn_mfma_f32_16x16x32_bf16(ah1, bf[t], acc[1][t], 0, 0, 0);
                acc[0][t] = __builtin_amdgcn_mfma_f32_16x16x32_bf16(al0, bf[t], acc[0][t], 0, 0, 0);
                acc[1][t] = __builtin_amdgcn_mfma_f32_16x16x32_bf16(al1, bf[t], acc[1][t], 0, 0, 0);
            }
        }
    }

#pragma unroll
    for (int ct = 0; ct < 2; ++ct) {
#pragma unroll
        for (int reg = 0; reg < 4; ++reg) {
            int co = wave * 32 + ct * 16 + l4 * 4 + reg;
            float bv = bias[co];
#pragma unroll
            for (int t = 0; t < 4; ++t) {
                int hh = h0 + (t >> 1);
                int ww = (t & 1) * 16 + l15;
                out[(((size_t)n * C_ + co) * H_ + hh) * W_ + ww] = acc[ct][t][reg] + bv;
            }
        }
    }
}

// ---------------------------------------------------------------------------
extern "C" void kernel_launch(void* const* d_in, const int* in_sizes, int n_in,
                              void* d_out, int out_size, void* d_ws, size_t ws_size,
                              hipStream_t stream) {
    const float* x       = (const float*)d_in[0];
    const float* w_pre   = (const float*)d_in[1];
    const float* b_pre   = (const float*)d_in[2];
    const float* alpha_p = (const float*)d_in[3];
    const float* w_post  = (const float*)d_in[4];
    const float* b_post  = (const float*)d_in[5];
    float* out = (float*)d_out;

    char* ws = (char*)d_ws;
    float*          wt_pre = (float*)ws;                        // 589,824 B
    unsigned short* pk_hi  = (unsigned short*)(ws + 655360);    // 294,912 B
    unsigned short* pk_lo  = (unsigned short*)(ws + 983040);    // 294,912 B
    float*          ybuf   = (float*)(ws + (2 << 20));          // ~100.7 MB

    {
        dim3 g((WELEM_ + 255) / 256), b(256);
        transpose_w_kio_kernel<<<g, b, 0, stream>>>(w_pre, wt_pre);
        pack_w_post_kernel<<<g, b, 0, stream>>>(w_post, pk_hi, pk_lo);
    }
    // 1) pre-conv (bit-exact Q=192 panels, static-unrolled) + bias + clip
    {
        dim3 g(NIMG_ * H_), b(256);
        conv_pre_blas_kernel<<<g, b, 0, stream>>>(x, wt_pre, b_pre, alpha_p, ybuf);
    }
    // 2) spiking scan fp32 (in place)  [EXACT]
    {
        int total = B_ * CHW_;
        dim3 g(total / 256), b(256);
        spike_scan_kernel<<<g, b, 0, stream>>>(ybuf, alpha_p);
    }
    // 3) post-conv via bf16 MFMA (hi+lo split) -> out
    {
        dim3 g(NIMG_ * 16), b(256);
        conv_post_mfma_kernel<<<g, b, 0, stream>>>(ybuf, pk_hi, pk_lo, b_post, out);
    }
}